// Round 1
// baseline (4482.264 us; speedup 1.0000x reference)
//
#include <hip/hip_runtime.h>
#include <hip/hip_bf16.h>
#include <math.h>

// Problem constants
#define PN   2048   // points per batch
#define PB   16     // batches
#define PG   128    // groups (= L tokens)
#define PM   32     // neighbors per group
#define PDM  384
#define PDI  768
#define PDS  16
#define PDTR 24
#define ROWS 2048   // B*G == B*L

// ---------------------------------------------------------------- FPS
__global__ __launch_bounds__(256) void fps_kernel(const float* __restrict__ xyz,
                                                  int* __restrict__ cidx) {
  const int b = blockIdx.x;
  const int tid = threadIdx.x;
  __shared__ float px[PN], py[PN], pz[PN], dmin[PN];
  __shared__ float wv[4]; __shared__ int wi[4]; __shared__ int curs;
  const float* base = xyz + (size_t)b * PN * 3;
  for (int j = tid; j < PN; j += 256) {
    px[j] = base[j*3+0]; py[j] = base[j*3+1]; pz[j] = base[j*3+2];
    dmin[j] = 1e10f;
  }
  if (tid == 0) curs = 0;
  __syncthreads();
  for (int g = 0; g < PG; ++g) {
    const int cur = curs;
    if (tid == 0) cidx[b*PG + g] = cur;
    const float cx = px[cur], cy = py[cur], cz = pz[cur];
    float bestv = -1.0f; int besti = 0;
    for (int j = tid; j < PN; j += 256) {
      float dx = __fsub_rn(px[j], cx);
      float dy = __fsub_rn(py[j], cy);
      float dz = __fsub_rn(pz[j], cz);
      float dd = __fadd_rn(__fadd_rn(__fmul_rn(dx,dx), __fmul_rn(dy,dy)), __fmul_rn(dz,dz));
      float dm = fminf(dmin[j], dd);
      dmin[j] = dm;
      if (dm > bestv) { bestv = dm; besti = j; }   // ascending j -> lowest idx on tie
    }
    #pragma unroll
    for (int off = 1; off < 64; off <<= 1) {
      float ov = __shfl_xor(bestv, off);
      int   oi = __shfl_xor(besti, off);
      if (ov > bestv || (ov == bestv && oi < besti)) { bestv = ov; besti = oi; }
    }
    if ((tid & 63) == 0) { wv[tid>>6] = bestv; wi[tid>>6] = besti; }
    __syncthreads();
    if (tid == 0) {
      float v = wv[0]; int bi = wi[0];
      for (int w = 1; w < 4; ++w)
        if (wv[w] > v || (wv[w] == v && wi[w] < bi)) { v = wv[w]; bi = wi[w]; }
      curs = bi;
    }
    __syncthreads();
  }
}

// ---------------------------------------------------------------- kNN + gather
__global__ __launch_bounds__(256) void knn_kernel(const float* __restrict__ xyz,
                                                  const int* __restrict__ cidx,
                                                  float* __restrict__ nbx,
                                                  float* __restrict__ centerb) {
  const int bg = blockIdx.x;
  const int b = bg >> 7;
  const int tid = threadIdx.x;
  __shared__ float d2s[PN];
  __shared__ float wv[4]; __shared__ int wi[4]; __shared__ int sel;
  const float* base = xyz + (size_t)b * PN * 3;
  const int ci = cidx[bg];
  const float cx = base[ci*3+0], cy = base[ci*3+1], cz = base[ci*3+2];
  if (tid == 0) { centerb[bg*3+0]=cx; centerb[bg*3+1]=cy; centerb[bg*3+2]=cz; }
  for (int j = tid; j < PN; j += 256) {
    float dx = __fsub_rn(cx, base[j*3+0]);
    float dy = __fsub_rn(cy, base[j*3+1]);
    float dz = __fsub_rn(cz, base[j*3+2]);
    d2s[j] = __fadd_rn(__fadd_rn(__fmul_rn(dx,dx), __fmul_rn(dy,dy)), __fmul_rn(dz,dz));
  }
  __syncthreads();
  for (int m = 0; m < PM; ++m) {
    float bestv = 1e38f; int besti = 0;
    for (int j = tid; j < PN; j += 256) {
      float v = d2s[j];
      if (v < bestv) { bestv = v; besti = j; }
    }
    #pragma unroll
    for (int off = 1; off < 64; off <<= 1) {
      float ov = __shfl_xor(bestv, off);
      int   oi = __shfl_xor(besti, off);
      if (ov < bestv || (ov == bestv && oi < besti)) { bestv = ov; besti = oi; }
    }
    if ((tid & 63) == 0) { wv[tid>>6] = bestv; wi[tid>>6] = besti; }
    __syncthreads();
    if (tid == 0) {
      float v = wv[0]; int bi = wi[0];
      for (int w = 1; w < 4; ++w)
        if (wv[w] < v || (wv[w] == v && wi[w] < bi)) { v = wv[w]; bi = wi[w]; }
      sel = bi;
      d2s[bi] = 1e38f;
    }
    __syncthreads();
    const int k = sel;
    if (tid == 0) {
      nbx[(bg*PM + m)*3 + 0] = base[k*3+0] - cx;
      nbx[(bg*PM + m)*3 + 1] = base[k*3+1] - cy;
      nbx[(bg*PM + m)*3 + 2] = base[k*3+2] - cz;
    }
  }
}

// ---------------------------------------------------------------- embed stage A+B (f1 -> f2, fg)
__global__ __launch_bounds__(256) void embed1_kernel(
    const float* __restrict__ nbx,
    const float* __restrict__ e1w1, const float* __restrict__ e1b1,
    const float* __restrict__ bn1g, const float* __restrict__ bn1b,
    const float* __restrict__ e1w2, const float* __restrict__ e1b2,
    float* __restrict__ f2, float* __restrict__ fg) {
  const int bg = blockIdx.x;
  const int tid = threadIdx.x;
  __shared__ float xs[PM*3];
  __shared__ float f1[PM][128];
  if (tid < PM*3) xs[tid] = nbx[bg*PM*3 + tid];
  __syncthreads();
  const float bnscale = rsqrtf(1.0f + 1e-5f);
  #pragma unroll
  for (int it = 0; it < 16; ++it) {
    int id = tid + it*256;
    int m = id >> 7, c = id & 127;
    float v = xs[m*3+0]*e1w1[c*3+0] + xs[m*3+1]*e1w1[c*3+1] + xs[m*3+2]*e1w1[c*3+2] + e1b1[c];
    v = v * (bn1g[c]*bnscale) + bn1b[c];
    f1[m][c] = fmaxf(v, 0.0f);
  }
  __syncthreads();
  const int e = tid;
  float acc[PM];
  const float bias = e1b2[e];
  #pragma unroll
  for (int m = 0; m < PM; ++m) acc[m] = bias;
  const float4* wrow = (const float4*)(e1w2 + (size_t)e*128);
  for (int k4 = 0; k4 < 32; ++k4) {
    float4 w = wrow[k4];
    #pragma unroll
    for (int m = 0; m < PM; ++m) {
      float4 a = *(const float4*)&f1[m][k4*4];
      acc[m] = fmaf(a.x, w.x, fmaf(a.y, w.y, fmaf(a.z, w.z, fmaf(a.w, w.w, acc[m]))));
    }
  }
  float mx = -1e30f;
  #pragma unroll
  for (int m = 0; m < PM; ++m) {
    f2[((size_t)bg*PM + m)*256 + e] = acc[m];
    mx = fmaxf(mx, acc[m]);
  }
  fg[(size_t)bg*256 + e] = mx;
}

// ---------------------------------------------------------------- embed stage C+D (+maxpool -> tokens)
__global__ __launch_bounds__(256) void embed2_kernel(
    const float* __restrict__ f2, const float* __restrict__ fg,
    const float* __restrict__ e2w1, const float* __restrict__ e2b1,
    const float* __restrict__ bn2g, const float* __restrict__ bn2b,
    const float* __restrict__ e2w2, const float* __restrict__ e2b2,
    float* __restrict__ tokens) {
  const int bg = blockIdx.x;
  const int tid = threadIdx.x;
  __shared__ float as[PM][512];   // 64 KB; reused as f3 after stage C
  #pragma unroll
  for (int it = 0; it < 64; ++it) {
    int id = tid + it*256;
    int m = id >> 9, c = id & 511;
    as[m][c] = (c < 256) ? fg[(size_t)bg*256 + c]
                         : f2[((size_t)bg*PM + m)*256 + (c - 256)];
  }
  __syncthreads();
  const float bnscale = rsqrtf(1.0f + 1e-5f);
  float r0[PM], r1[PM];
  {
    const int o0 = tid, o1 = tid + 256;
    const float b0 = e2b1[o0], b1 = e2b1[o1];
    #pragma unroll
    for (int m = 0; m < PM; ++m) { r0[m] = b0; r1[m] = b1; }
    const float4* w0 = (const float4*)(e2w1 + (size_t)o0*512);
    const float4* w1 = (const float4*)(e2w1 + (size_t)o1*512);
    for (int k4 = 0; k4 < 128; ++k4) {
      float4 wa = w0[k4], wb = w1[k4];
      #pragma unroll
      for (int m = 0; m < PM; ++m) {
        float4 a = *(const float4*)&as[m][k4*4];
        r0[m] = fmaf(a.x, wa.x, fmaf(a.y, wa.y, fmaf(a.z, wa.z, fmaf(a.w, wa.w, r0[m]))));
        r1[m] = fmaf(a.x, wb.x, fmaf(a.y, wb.y, fmaf(a.z, wb.z, fmaf(a.w, wb.w, r1[m]))));
      }
    }
    const float s0 = bn2g[o0]*bnscale, s1 = bn2g[o1]*bnscale;
    const float c0 = bn2b[o0], c1 = bn2b[o1];
    #pragma unroll
    for (int m = 0; m < PM; ++m) {
      r0[m] = fmaxf(fmaf(r0[m], s0, c0), 0.0f);
      r1[m] = fmaxf(fmaf(r1[m], s1, c1), 0.0f);
    }
  }
  __syncthreads();
  #pragma unroll
  for (int m = 0; m < PM; ++m) { as[m][tid] = r0[m]; as[m][tid+256] = r1[m]; }
  __syncthreads();
  for (int e = tid; e < PDM; e += 256) {
    float acc[PM];
    const float bias = e2b2[e];
    #pragma unroll
    for (int m = 0; m < PM; ++m) acc[m] = bias;
    const float4* w = (const float4*)(e2w2 + (size_t)e*512);
    for (int k4 = 0; k4 < 128; ++k4) {
      float4 wv = w[k4];
      #pragma unroll
      for (int m = 0; m < PM; ++m) {
        float4 a = *(const float4*)&as[m][k4*4];
        acc[m] = fmaf(a.x, wv.x, fmaf(a.y, wv.y, fmaf(a.z, wv.z, fmaf(a.w, wv.w, acc[m]))));
      }
    }
    float mx = -1e30f;
    #pragma unroll
    for (int m = 0; m < PM; ++m) mx = fmaxf(mx, acc[m]);
    tokens[(size_t)bg*PDM + e] = mx;
  }
}

// ---------------------------------------------------------------- pos MLP (+ add into h)
__global__ __launch_bounds__(128) void pos_kernel(
    const float* __restrict__ centerb,
    const float* __restrict__ pw1, const float* __restrict__ pb1,
    const float* __restrict__ pw2, const float* __restrict__ pb2,
    float* __restrict__ h) {
  const int bg = blockIdx.x;
  const int tid = threadIdx.x;
  __shared__ float t1[128];
  const float cx = centerb[bg*3+0], cy = centerb[bg*3+1], cz = centerb[bg*3+2];
  {
    const int c = tid;
    float v = cx*pw1[c*3+0] + cy*pw1[c*3+1] + cz*pw1[c*3+2] + pb1[c];
    float u = 0.7978845608028654f * (v + 0.044715f*v*v*v);
    t1[c] = 0.5f*v*(1.0f + tanhf(u));   // jax.nn.gelu (tanh approx, default)
  }
  __syncthreads();
  for (int e = tid; e < PDM; e += 128) {
    float acc = pb2[e];
    const float4* w = (const float4*)(pw2 + (size_t)e*128);
    const float4* a = (const float4*)t1;
    for (int k4 = 0; k4 < 32; ++k4) {
      float4 wv = w[k4], av = a[k4];
      acc = fmaf(av.x, wv.x, fmaf(av.y, wv.y, fmaf(av.z, wv.z, fmaf(av.w, wv.w, acc))));
    }
    h[(size_t)bg*PDM + e] += acc;   // tokens already in h
  }
}

// ---------------------------------------------------------------- prenorm (residual update + LN)
__global__ __launch_bounds__(128) void prenorm_kernel(
    const float* __restrict__ h, float* __restrict__ res,
    const float* __restrict__ w, const float* __restrict__ bb,
    float* __restrict__ xo, int first) {
  const int row = blockIdx.x;
  const int tid = threadIdx.x;
  __shared__ float s1[2], s2[2];
  float v[3];
  #pragma unroll
  for (int i = 0; i < 3; ++i) {
    int j = tid + i*128;
    float r = h[(size_t)row*PDM + j];
    if (!first) r += res[(size_t)row*PDM + j];
    res[(size_t)row*PDM + j] = r;
    v[i] = r;
  }
  float ss = v[0] + v[1] + v[2];
  #pragma unroll
  for (int off = 1; off < 64; off <<= 1) ss += __shfl_xor(ss, off);
  if ((tid & 63) == 0) s1[tid>>6] = ss;
  __syncthreads();
  const float mu = (s1[0] + s1[1]) * (1.0f/384.0f);
  float q = 0.f;
  #pragma unroll
  for (int i = 0; i < 3; ++i) { float d = v[i] - mu; q += d*d; }
  #pragma unroll
  for (int off = 1; off < 64; off <<= 1) q += __shfl_xor(q, off);
  if ((tid & 63) == 0) s2[tid>>6] = q;
  __syncthreads();
  const float rs = rsqrtf((s2[0] + s2[1]) * (1.0f/384.0f) + 1e-5f);
  #pragma unroll
  for (int i = 0; i < 3; ++i) {
    int j = tid + i*128;
    xo[(size_t)row*PDM + j] = (v[i] - mu) * rs * w[j] + bb[j];
  }
}

// ---------------------------------------------------------------- final LN -> d_out
__global__ __launch_bounds__(128) void final_kernel(
    const float* __restrict__ h, const float* __restrict__ res,
    const float* __restrict__ w, const float* __restrict__ bb,
    float* __restrict__ out) {
  const int row = blockIdx.x;
  const int tid = threadIdx.x;
  __shared__ float s1[2], s2[2];
  float v[3];
  #pragma unroll
  for (int i = 0; i < 3; ++i) {
    int j = tid + i*128;
    v[i] = h[(size_t)row*PDM + j] + res[(size_t)row*PDM + j];
  }
  float ss = v[0] + v[1] + v[2];
  #pragma unroll
  for (int off = 1; off < 64; off <<= 1) ss += __shfl_xor(ss, off);
  if ((tid & 63) == 0) s1[tid>>6] = ss;
  __syncthreads();
  const float mu = (s1[0] + s1[1]) * (1.0f/384.0f);
  float q = 0.f;
  #pragma unroll
  for (int i = 0; i < 3; ++i) { float d = v[i] - mu; q += d*d; }
  #pragma unroll
  for (int off = 1; off < 64; off <<= 1) q += __shfl_xor(q, off);
  if ((tid & 63) == 0) s2[tid>>6] = q;
  __syncthreads();
  const float rs = rsqrtf((s2[0] + s2[1]) * (1.0f/384.0f) + 1e-5f);
  #pragma unroll
  for (int i = 0; i < 3; ++i) {
    int j = tid + i*128;
    out[(size_t)row*PDM + j] = (v[i] - mu) * rs * w[j] + bb[j];
  }
}

// ---------------------------------------------------------------- generic fp32 GEMM  C = A(MxK) * W(NxK)^T
template<int BM, int BN>
__global__ __launch_bounds__(256) void gemm_tt(const float* __restrict__ A,
                                               const float* __restrict__ W,
                                               float* __restrict__ C,
                                               int K, int Ndim) {
  constexpr int TM = BM/16;
  __shared__ float As[16][BM];
  __shared__ float Ws[16][BN];
  const int tid = threadIdx.x;
  const int m0 = blockIdx.y * BM;
  const int n0 = blockIdx.x * BN;
  const int ty = tid >> 4, tx = tid & 15;
  float acc[TM][4];
  #pragma unroll
  for (int i = 0; i < TM; ++i)
    #pragma unroll
    for (int j = 0; j < 4; ++j) acc[i][j] = 0.f;
  for (int k0 = 0; k0 < K; k0 += 16) {
    if (tid < BM*4) {
      int r = tid >> 2, kq = (tid & 3) * 4;
      float4 a = *(const float4*)(A + (size_t)(m0+r)*K + k0 + kq);
      As[kq+0][r]=a.x; As[kq+1][r]=a.y; As[kq+2][r]=a.z; As[kq+3][r]=a.w;
    }
    if (tid < BN*4) {
      int r = tid >> 2, kq = (tid & 3) * 4;
      float4 w = *(const float4*)(W + (size_t)(n0+r)*K + k0 + kq);
      Ws[kq+0][r]=w.x; Ws[kq+1][r]=w.y; Ws[kq+2][r]=w.z; Ws[kq+3][r]=w.w;
    }
    __syncthreads();
    #pragma unroll
    for (int kk = 0; kk < 16; ++kk) {
      float av[TM], wv[4];
      if constexpr (TM == 4) {
        float4 t = *(const float4*)&As[kk][ty*4];
        av[0]=t.x; av[1]=t.y; av[2]=t.z; av[3]=t.w;
      } else {
        float2 t = *(const float2*)&As[kk][ty*2];
        av[0]=t.x; av[1]=t.y;
      }
      { float4 t = *(const float4*)&Ws[kk][tx*4]; wv[0]=t.x; wv[1]=t.y; wv[2]=t.z; wv[3]=t.w; }
      #pragma unroll
      for (int i = 0; i < TM; ++i)
        #pragma unroll
        for (int j = 0; j < 4; ++j) acc[i][j] = fmaf(av[i], wv[j], acc[i][j]);
    }
    __syncthreads();
  }
  #pragma unroll
  for (int i = 0; i < TM; ++i) {
    float4 o; o.x = acc[i][0]; o.y = acc[i][1]; o.z = acc[i][2]; o.w = acc[i][3];
    *(float4*)(C + (size_t)(m0 + ty*TM + i)*Ndim + n0 + tx*4) = o;
  }
}

// ---------------------------------------------------------------- conv1d(DC=4, causal) + silu
__global__ __launch_bounds__(256) void conv_kernel(const float* __restrict__ xz,
                                                   const float* __restrict__ cw,
                                                   const float* __restrict__ cb,
                                                   float* __restrict__ xin) {
  const int row = blockIdx.y;
  const int d = blockIdx.x*256 + threadIdx.x;
  const int l = row & 127;
  const int bbase = row - l;
  float acc = cb[d];
  #pragma unroll
  for (int k = 0; k < 4; ++k) {
    int ll = l + k - 3;
    if (ll >= 0) acc = fmaf(xz[(size_t)(bbase+ll)*1536 + d], cw[d*4+k], acc);
  }
  float s = 1.0f / (1.0f + expf(-acc));
  xin[(size_t)row*PDI + d] = acc * s;
}

// ---------------------------------------------------------------- dbl = xin @ xp_w^T  (N=56)
__global__ __launch_bounds__(64) void xp_kernel(const float* __restrict__ xin,
                                                const float* __restrict__ w,
                                                float* __restrict__ dbl) {
  const int row = blockIdx.x;
  const int e = threadIdx.x;
  if (e >= 56) return;
  const float4* a = (const float4*)(xin + (size_t)row*PDI);
  const float4* wr = (const float4*)(w + (size_t)e*PDI);
  float acc = 0.f;
  for (int k = 0; k < 192; ++k) {
    float4 av = a[k], wv = wr[k];
    acc = fmaf(av.x, wv.x, fmaf(av.y, wv.y, fmaf(av.z, wv.z, fmaf(av.w, wv.w, acc))));
  }
  dbl[(size_t)row*56 + e] = acc;
}

// ---------------------------------------------------------------- dt = softplus(dbl[:, :24] @ dt_w^T + dt_b)
__global__ __launch_bounds__(256) void dt_kernel(const float* __restrict__ dbl,
                                                 const float* __restrict__ dtw,
                                                 const float* __restrict__ dtbias,
                                                 float* __restrict__ dt) {
  const int row = blockIdx.y;
  const int d = blockIdx.x*256 + threadIdx.x;
  const float* br = dbl + (size_t)row*56;
  const float* wr = dtw + (size_t)d*24;
  float acc = dtbias[d];
  #pragma unroll
  for (int r = 0; r < 24; ++r) acc = fmaf(br[r], wr[r], acc);
  dt[(size_t)row*PDI + d] = log1pf(expf(-fabsf(acc))) + fmaxf(acc, 0.0f);
}

// ---------------------------------------------------------------- selective scan
__global__ __launch_bounds__(256) void scan_kernel(const float* __restrict__ dt,
                                                   const float* __restrict__ xin,
                                                   const float* __restrict__ dbl,
                                                   const float* __restrict__ alog,
                                                   const float* __restrict__ dp,
                                                   float* __restrict__ y) {
  const int s = threadIdx.x & 15;
  const int dl = threadIdx.x >> 4;
  const int d = blockIdx.x*16 + dl;
  const int b = blockIdx.y;
  const float A = -expf(alog[d*16 + s]);
  const float Dv = dp[d];
  float h = 0.f;
  for (int l = 0; l < 128; ++l) {
    const int ro = b*128 + l;
    float dtv = dt[(size_t)ro*PDI + d];
    float xv  = xin[(size_t)ro*PDI + d];
    float Bv  = dbl[(size_t)ro*56 + 24 + s];
    float Cv  = dbl[(size_t)ro*56 + 40 + s];
    float dA = expf(dtv * A);
    h = fmaf(dA, h, dtv * xv * Bv);
    float p = h * Cv;
    p += __shfl_xor(p, 1);
    p += __shfl_xor(p, 2);
    p += __shfl_xor(p, 4);
    p += __shfl_xor(p, 8);
    if (s == 0) y[(size_t)ro*PDI + d] = fmaf(Dv, xv, p);
  }
}

// ---------------------------------------------------------------- y *= silu(z)
__global__ __launch_bounds__(256) void gate_kernel(float* __restrict__ y,
                                                   const float* __restrict__ xz) {
  const int row = blockIdx.y;
  const int d = blockIdx.x*256 + threadIdx.x;
  float z = xz[(size_t)row*1536 + 768 + d];
  float s = 1.0f / (1.0f + expf(-z));
  y[(size_t)row*PDI + d] *= z * s;
}

// ---------------------------------------------------------------- host
extern "C" void kernel_launch(void* const* d_in, const int* in_sizes, int n_in,
                              void* d_out, int out_size, void* d_ws, size_t ws_size,
                              hipStream_t stream) {
  const float* xyz    = (const float*)d_in[0];
  const float* e1w1   = (const float*)d_in[1];
  const float* e1b1   = (const float*)d_in[2];
  const float* bn1g   = (const float*)d_in[3];
  const float* bn1b   = (const float*)d_in[4];
  const float* e1w2   = (const float*)d_in[5];
  const float* e1b2   = (const float*)d_in[6];
  const float* e2w1   = (const float*)d_in[7];
  const float* e2b1   = (const float*)d_in[8];
  const float* bn2g   = (const float*)d_in[9];
  const float* bn2b   = (const float*)d_in[10];
  const float* e2w2   = (const float*)d_in[11];
  const float* e2b2   = (const float*)d_in[12];
  const float* pw1    = (const float*)d_in[13];
  const float* pb1    = (const float*)d_in[14];
  const float* pw2    = (const float*)d_in[15];
  const float* pb2    = (const float*)d_in[16];
  const float* in_w   = (const float*)d_in[17];
  const float* conv_w = (const float*)d_in[18];
  const float* conv_b = (const float*)d_in[19];
  const float* xp_w   = (const float*)d_in[20];
  const float* dt_w   = (const float*)d_in[21];
  const float* dt_b   = (const float*)d_in[22];
  const float* A_log  = (const float*)d_in[23];
  const float* Dp     = (const float*)d_in[24];
  const float* out_w  = (const float*)d_in[25];
  const float* lnw    = (const float*)d_in[26];
  const float* lnb    = (const float*)d_in[27];
  const float* fnw    = (const float*)d_in[28];
  const float* fnb    = (const float*)d_in[29];

  char* ws = (char*)d_ws;
  int*   cidx    = (int*)  (ws + 0);           //    8192
  float* centerb = (float*)(ws + 8192);        //   24576
  float* nbx     = (float*)(ws + 32768);       //  786432
  float* f2      = (float*)(ws + 819200);      // 67108864
  float* fg      = (float*)(ws + 67928064);    //  2097152
  float* hbuf    = (float*)(ws + 70025216);    //  3145728
  float* resid   = (float*)(ws + 73170944);    //  3145728
  float* xln     = (float*)(ws + 76316672);    //  3145728
  float* xz      = (float*)(ws + 79462400);    // 12582912
  float* xin     = (float*)(ws + 92045312);    //  6291456
  float* dbl     = (float*)(ws + 98336768);    //   458752
  float* dtb     = (float*)(ws + 98795520);    //  6291456
  float* ybuf    = (float*)(ws + 105086976);   //  6291456  -> total ~111.4 MB

  fps_kernel<<<PB, 256, 0, stream>>>(xyz, cidx);
  knn_kernel<<<ROWS, 256, 0, stream>>>(xyz, cidx, nbx, centerb);
  embed1_kernel<<<ROWS, 256, 0, stream>>>(nbx, e1w1, e1b1, bn1g, bn1b, e1w2, e1b2, f2, fg);
  embed2_kernel<<<ROWS, 256, 0, stream>>>(f2, fg, e2w1, e2b1, bn2g, bn2b, e2w2, e2b2, hbuf);
  pos_kernel<<<ROWS, 128, 0, stream>>>(centerb, pw1, pb1, pw2, pb2, hbuf);

  for (int i = 0; i < 12; ++i) {
    prenorm_kernel<<<ROWS, 128, 0, stream>>>(hbuf, resid, lnw + i*384, lnb + i*384, xln, (i == 0) ? 1 : 0);
    gemm_tt<64,64><<<dim3(24, 32), 256, 0, stream>>>(xln, in_w + (size_t)i*1536*384, xz, 384, 1536);
    conv_kernel<<<dim3(3, ROWS), 256, 0, stream>>>(xz, conv_w + (size_t)i*768*4, conv_b + (size_t)i*768, xin);
    xp_kernel<<<ROWS, 64, 0, stream>>>(xin, xp_w + (size_t)i*56*768, dbl);
    dt_kernel<<<dim3(3, ROWS), 256, 0, stream>>>(dbl, dt_w + (size_t)i*768*24, dt_b + (size_t)i*768, dtb);
    scan_kernel<<<dim3(48, PB), 256, 0, stream>>>(dtb, xin, dbl, A_log + (size_t)i*768*16, Dp + (size_t)i*768, ybuf);
    gate_kernel<<<dim3(3, ROWS), 256, 0, stream>>>(ybuf, xz);
    gemm_tt<32,64><<<dim3(6, 64), 256, 0, stream>>>(ybuf, out_w + (size_t)i*384*768, hbuf, 768, 384);
  }

  final_kernel<<<ROWS, 128, 0, stream>>>(hbuf, resid, fnw, fnb, (float*)d_out);
}

// Round 2
// 2603.958 us; speedup vs baseline: 1.7213x; 1.7213x over previous
//
#include <hip/hip_runtime.h>
#include <hip/hip_bf16.h>
#include <math.h>

#define PN   2048
#define PB   16
#define PG   128
#define PM   32
#define PDM  384
#define PDI  768
#define ROWS 2048   // B*G == B*L

typedef unsigned short ushort_t;
typedef __attribute__((ext_vector_type(8))) short bf8;
typedef __attribute__((ext_vector_type(4))) float f4;

__device__ __forceinline__ ushort_t f2bf(float x) {
  unsigned int u = __float_as_uint(x);
  unsigned int r = (u + 0x7FFFu + ((u >> 16) & 1u)) >> 16;
  return (ushort_t)r;
}

#define GL2L(gp, lp) __builtin_amdgcn_global_load_lds((const __attribute__((address_space(1))) void*)(gp), (__attribute__((address_space(3))) void*)(lp), 16, 0, 0)

// ---------------------------------------------------------------- fp32 -> bf16 convert
__global__ __launch_bounds__(256) void cvt_kernel(const float* __restrict__ s,
                                                  ushort_t* __restrict__ d, int n) {
  int i = blockIdx.x*256 + threadIdx.x;
  if (i < n) d[i] = f2bf(s[i]);
}

// ---------------------------------------------------------------- FPS
__global__ __launch_bounds__(256) void fps_kernel(const float* __restrict__ xyz,
                                                  int* __restrict__ cidx) {
  const int b = blockIdx.x;
  const int tid = threadIdx.x;
  __shared__ float px[PN], py[PN], pz[PN], dmin[PN];
  __shared__ float wv[4]; __shared__ int wi[4]; __shared__ int curs;
  const float* base = xyz + (size_t)b * PN * 3;
  for (int j = tid; j < PN; j += 256) {
    px[j] = base[j*3+0]; py[j] = base[j*3+1]; pz[j] = base[j*3+2];
    dmin[j] = 1e10f;
  }
  if (tid == 0) curs = 0;
  __syncthreads();
  for (int g = 0; g < PG; ++g) {
    const int cur = curs;
    if (tid == 0) cidx[b*PG + g] = cur;
    const float cx = px[cur], cy = py[cur], cz = pz[cur];
    float bestv = -1.0f; int besti = 0;
    for (int j = tid; j < PN; j += 256) {
      float dx = __fsub_rn(px[j], cx);
      float dy = __fsub_rn(py[j], cy);
      float dz = __fsub_rn(pz[j], cz);
      float dd = __fadd_rn(__fadd_rn(__fmul_rn(dx,dx), __fmul_rn(dy,dy)), __fmul_rn(dz,dz));
      float dm = fminf(dmin[j], dd);
      dmin[j] = dm;
      if (dm > bestv) { bestv = dm; besti = j; }
    }
    #pragma unroll
    for (int off = 1; off < 64; off <<= 1) {
      float ov = __shfl_xor(bestv, off);
      int   oi = __shfl_xor(besti, off);
      if (ov > bestv || (ov == bestv && oi < besti)) { bestv = ov; besti = oi; }
    }
    if ((tid & 63) == 0) { wv[tid>>6] = bestv; wi[tid>>6] = besti; }
    __syncthreads();
    if (tid == 0) {
      float v = wv[0]; int bi = wi[0];
      for (int w = 1; w < 4; ++w)
        if (wv[w] > v || (wv[w] == v && wi[w] < bi)) { v = wv[w]; bi = wi[w]; }
      curs = bi;
    }
    __syncthreads();
  }
}

// ---------------------------------------------------------------- kNN + gather
__global__ __launch_bounds__(256) void knn_kernel(const float* __restrict__ xyz,
                                                  const int* __restrict__ cidx,
                                                  float* __restrict__ nbx,
                                                  float* __restrict__ centerb) {
  const int bg = blockIdx.x;
  const int b = bg >> 7;
  const int tid = threadIdx.x;
  __shared__ float d2s[PN];
  __shared__ float wv[4]; __shared__ int wi[4]; __shared__ int sel;
  const float* base = xyz + (size_t)b * PN * 3;
  const int ci = cidx[bg];
  const float cx = base[ci*3+0], cy = base[ci*3+1], cz = base[ci*3+2];
  if (tid == 0) { centerb[bg*3+0]=cx; centerb[bg*3+1]=cy; centerb[bg*3+2]=cz; }
  for (int j = tid; j < PN; j += 256) {
    float dx = __fsub_rn(cx, base[j*3+0]);
    float dy = __fsub_rn(cy, base[j*3+1]);
    float dz = __fsub_rn(cz, base[j*3+2]);
    d2s[j] = __fadd_rn(__fadd_rn(__fmul_rn(dx,dx), __fmul_rn(dy,dy)), __fmul_rn(dz,dz));
  }
  __syncthreads();
  for (int m = 0; m < PM; ++m) {
    float bestv = 1e38f; int besti = 0;
    for (int j = tid; j < PN; j += 256) {
      float v = d2s[j];
      if (v < bestv) { bestv = v; besti = j; }
    }
    #pragma unroll
    for (int off = 1; off < 64; off <<= 1) {
      float ov = __shfl_xor(bestv, off);
      int   oi = __shfl_xor(besti, off);
      if (ov < bestv || (ov == bestv && oi < besti)) { bestv = ov; besti = oi; }
    }
    if ((tid & 63) == 0) { wv[tid>>6] = bestv; wi[tid>>6] = besti; }
    __syncthreads();
    if (tid == 0) {
      float v = wv[0]; int bi = wi[0];
      for (int w = 1; w < 4; ++w)
        if (wv[w] < v || (wv[w] == v && wi[w] < bi)) { v = wv[w]; bi = wi[w]; }
      sel = bi;
      d2s[bi] = 1e38f;
    }
    __syncthreads();
    const int k = sel;
    if (tid == 0) {
      nbx[(bg*PM + m)*3 + 0] = base[k*3+0] - cx;
      nbx[(bg*PM + m)*3 + 1] = base[k*3+1] - cy;
      nbx[(bg*PM + m)*3 + 2] = base[k*3+2] - cz;
    }
  }
}

// ---------------------------------------------------------------- embed stage A+B -> concat (bf16)
// concat[row=bg*32+m][c]: c<256 -> fg[c] (group max), c>=256 -> f2[m][c-256]
__global__ __launch_bounds__(256) void embed1_kernel(
    const float* __restrict__ nbx,
    const float* __restrict__ e1w1, const float* __restrict__ e1b1,
    const float* __restrict__ bn1g, const float* __restrict__ bn1b,
    const float* __restrict__ e1w2, const float* __restrict__ e1b2,
    ushort_t* __restrict__ concat) {
  const int bg = blockIdx.x;
  const int tid = threadIdx.x;
  __shared__ float xs[PM*3];
  __shared__ float f1[PM][128];
  if (tid < PM*3) xs[tid] = nbx[bg*PM*3 + tid];
  __syncthreads();
  const float bnscale = rsqrtf(1.0f + 1e-5f);
  #pragma unroll
  for (int it = 0; it < 16; ++it) {
    int id = tid + it*256;
    int m = id >> 7, c = id & 127;
    float v = xs[m*3+0]*e1w1[c*3+0] + xs[m*3+1]*e1w1[c*3+1] + xs[m*3+2]*e1w1[c*3+2] + e1b1[c];
    v = v * (bn1g[c]*bnscale) + bn1b[c];
    f1[m][c] = fmaxf(v, 0.0f);
  }
  __syncthreads();
  const int e = tid;
  float acc[PM];
  const float bias = e1b2[e];
  #pragma unroll
  for (int m = 0; m < PM; ++m) acc[m] = bias;
  const float4* wrow = (const float4*)(e1w2 + (size_t)e*128);
  for (int k4 = 0; k4 < 32; ++k4) {
    float4 w = wrow[k4];
    #pragma unroll
    for (int m = 0; m < PM; ++m) {
      float4 a = *(const float4*)&f1[m][k4*4];
      acc[m] = fmaf(a.x, w.x, fmaf(a.y, w.y, fmaf(a.z, w.z, fmaf(a.w, w.w, acc[m]))));
    }
  }
  float mx = -1e30f;
  #pragma unroll
  for (int m = 0; m < PM; ++m) {
    concat[((size_t)bg*PM + m)*512 + 256 + e] = f2bf(acc[m]);
    mx = fmaxf(mx, acc[m]);
  }
  ushort_t mxb = f2bf(mx);
  #pragma unroll
  for (int m = 0; m < PM; ++m)
    concat[((size_t)bg*PM + m)*512 + e] = mxb;
}

// ---------------------------------------------------------------- bf16 MFMA GEMM  C = A(M,K) @ W(N,K)^T
// m97 structure: fragment-ordered LDS, global_load_lds w=16, 2-barrier K-loop.
// Waves 2x2; wave computes MT x NT tiles of 16x16. BM=32*MT, BN=32*NT.
// EPI 0: fp32 store. EPI 1: (acc+p0)*(p1*bnscale)+p2, relu, bf16 store.
// EPI 2: group(32-row) max + p0 bias -> fp32 tokens (requires MT=4).
template<int MT, int NT, int EPI>
__global__ __launch_bounds__(256) void mfma_gemm(
    const ushort_t* __restrict__ A, int lda,
    const ushort_t* __restrict__ W, int ldw,
    float* __restrict__ Cf, ushort_t* __restrict__ Cb, int ldc, int K,
    const float* __restrict__ p0, const float* __restrict__ p1,
    const float* __restrict__ p2) {
  static_assert(EPI != 2 || MT == 4, "groupmax needs MT=4");
  constexpr int AT = 2*MT, BT = 2*NT;
  __shared__ __align__(16) ushort_t As[AT*64*8];
  __shared__ __align__(16) ushort_t Bs[BT*64*8];
  const int tid = threadIdx.x;
  const int wid = tid >> 6, lane = tid & 63;
  const int wr = wid >> 1, wc = wid & 1;
  const int q = lane >> 4, r16 = lane & 15;
  const int m0 = blockIdx.y * (32*MT);
  const int n0 = blockIdx.x * (32*NT);
  f4 acc[MT][NT];
  #pragma unroll
  for (int i = 0; i < MT; ++i)
    #pragma unroll
    for (int j = 0; j < NT; ++j) { f4 z = {0.f,0.f,0.f,0.f}; acc[i][j] = z; }

  const int kc = K >> 5;
  for (int k = 0; k < kc; ++k) {
    const int k0 = k*32 + q*8;
    #pragma unroll
    for (int t = wid; t < AT; t += 4)
      GL2L(A + (size_t)(m0 + t*16 + r16)*lda + k0, As + t*512);
    #pragma unroll
    for (int t = wid; t < BT; t += 4)
      GL2L(W + (size_t)(n0 + t*16 + r16)*ldw + k0, Bs + t*512);
    __syncthreads();
    bf8 af[MT], bfr[NT];
    #pragma unroll
    for (int i = 0; i < MT; ++i)
      af[i] = *(const bf8*)(As + ((size_t)((wr*MT+i)*64 + lane))*8);
    #pragma unroll
    for (int j = 0; j < NT; ++j)
      bfr[j] = *(const bf8*)(Bs + ((size_t)((wc*NT+j)*64 + lane))*8);
    #pragma unroll
    for (int i = 0; i < MT; ++i)
      #pragma unroll
      for (int j = 0; j < NT; ++j)
        acc[i][j] = __builtin_amdgcn_mfma_f32_16x16x32_bf16(af[i], bfr[j], acc[i][j], 0, 0, 0);
    __syncthreads();
  }

  // C/D layout: col = lane&15, row = (lane>>4)*4 + reg  [m89/m91 verified]
  if constexpr (EPI == 0) {
    #pragma unroll
    for (int i = 0; i < MT; ++i) {
      const int row = m0 + (wr*MT+i)*16 + q*4;
      #pragma unroll
      for (int j = 0; j < NT; ++j) {
        const int col = n0 + (wc*NT+j)*16 + r16;
        #pragma unroll
        for (int r = 0; r < 4; ++r)
          Cf[(size_t)(row+r)*ldc + col] = acc[i][j][r];
      }
    }
  } else if constexpr (EPI == 1) {
    const float bns = rsqrtf(1.0f + 1e-5f);
    #pragma unroll
    for (int j = 0; j < NT; ++j) {
      const int col = n0 + (wc*NT+j)*16 + r16;
      const float b1 = p0[col], sg = p1[col]*bns, b2 = p2[col];
      #pragma unroll
      for (int i = 0; i < MT; ++i) {
        const int row = m0 + (wr*MT+i)*16 + q*4;
        #pragma unroll
        for (int r = 0; r < 4; ++r) {
          float v = fmaxf(fmaf(acc[i][j][r] + b1, sg, b2), 0.0f);
          Cb[(size_t)(row+r)*ldc + col] = f2bf(v);
        }
      }
    }
  } else {
    #pragma unroll
    for (int j = 0; j < NT; ++j) {
      const int col = n0 + (wc*NT+j)*16 + r16;
      float tm[4];
      #pragma unroll
      for (int i = 0; i < 4; ++i) {
        float t = fmaxf(fmaxf(acc[i][j][0], acc[i][j][1]), fmaxf(acc[i][j][2], acc[i][j][3]));
        t = fmaxf(t, __shfl_xor(t, 16));
        t = fmaxf(t, __shfl_xor(t, 32));
        tm[i] = t;
      }
      const float bias = p0[col];
      if (lane < 16) {
        const int g0 = (m0 >> 5) + wr*2;
        Cf[(size_t)g0*ldc + col]     = fmaxf(tm[0], tm[1]) + bias;
        Cf[(size_t)(g0+1)*ldc + col] = fmaxf(tm[2], tm[3]) + bias;
      }
    }
  }
}

// ---------------------------------------------------------------- pos MLP (+ add into h)
__global__ __launch_bounds__(128) void pos_kernel(
    const float* __restrict__ centerb,
    const float* __restrict__ pw1, const float* __restrict__ pb1,
    const float* __restrict__ pw2, const float* __restrict__ pb2,
    float* __restrict__ h) {
  const int bg = blockIdx.x;
  const int tid = threadIdx.x;
  __shared__ float t1[128];
  const float cx = centerb[bg*3+0], cy = centerb[bg*3+1], cz = centerb[bg*3+2];
  {
    const int c = tid;
    float v = cx*pw1[c*3+0] + cy*pw1[c*3+1] + cz*pw1[c*3+2] + pb1[c];
    float u = 0.7978845608028654f * (v + 0.044715f*v*v*v);
    t1[c] = 0.5f*v*(1.0f + tanhf(u));
  }
  __syncthreads();
  for (int e = tid; e < PDM; e += 128) {
    float acc = pb2[e];
    const float4* w = (const float4*)(pw2 + (size_t)e*128);
    const float4* a = (const float4*)t1;
    for (int k4 = 0; k4 < 32; ++k4) {
      float4 wv = w[k4], av = a[k4];
      acc = fmaf(av.x, wv.x, fmaf(av.y, wv.y, fmaf(av.z, wv.z, fmaf(av.w, wv.w, acc))));
    }
    h[(size_t)bg*PDM + e] += acc;
  }
}

// ---------------------------------------------------------------- prenorm (residual update + LN) -> bf16
__global__ __launch_bounds__(128) void prenorm_kernel(
    const float* __restrict__ h, float* __restrict__ res,
    const float* __restrict__ w, const float* __restrict__ bb,
    ushort_t* __restrict__ xo, int first) {
  const int row = blockIdx.x;
  const int tid = threadIdx.x;
  __shared__ float s1[2], s2[2];
  float v[3];
  #pragma unroll
  for (int i = 0; i < 3; ++i) {
    int j = tid + i*128;
    float r = h[(size_t)row*PDM + j];
    if (!first) r += res[(size_t)row*PDM + j];
    res[(size_t)row*PDM + j] = r;
    v[i] = r;
  }
  float ss = v[0] + v[1] + v[2];
  #pragma unroll
  for (int off = 1; off < 64; off <<= 1) ss += __shfl_xor(ss, off);
  if ((tid & 63) == 0) s1[tid>>6] = ss;
  __syncthreads();
  const float mu = (s1[0] + s1[1]) * (1.0f/384.0f);
  float qq = 0.f;
  #pragma unroll
  for (int i = 0; i < 3; ++i) { float d = v[i] - mu; qq += d*d; }
  #pragma unroll
  for (int off = 1; off < 64; off <<= 1) qq += __shfl_xor(qq, off);
  if ((tid & 63) == 0) s2[tid>>6] = qq;
  __syncthreads();
  const float rs = rsqrtf((s2[0] + s2[1]) * (1.0f/384.0f) + 1e-5f);
  #pragma unroll
  for (int i = 0; i < 3; ++i) {
    int j = tid + i*128;
    xo[(size_t)row*PDM + j] = f2bf((v[i] - mu) * rs * w[j] + bb[j]);
  }
}

// ---------------------------------------------------------------- final LN -> d_out
__global__ __launch_bounds__(128) void final_kernel(
    const float* __restrict__ h, const float* __restrict__ res,
    const float* __restrict__ w, const float* __restrict__ bb,
    float* __restrict__ out) {
  const int row = blockIdx.x;
  const int tid = threadIdx.x;
  __shared__ float s1[2], s2[2];
  float v[3];
  #pragma unroll
  for (int i = 0; i < 3; ++i) {
    int j = tid + i*128;
    v[i] = h[(size_t)row*PDM + j] + res[(size_t)row*PDM + j];
  }
  float ss = v[0] + v[1] + v[2];
  #pragma unroll
  for (int off = 1; off < 64; off <<= 1) ss += __shfl_xor(ss, off);
  if ((tid & 63) == 0) s1[tid>>6] = ss;
  __syncthreads();
  const float mu = (s1[0] + s1[1]) * (1.0f/384.0f);
  float qq = 0.f;
  #pragma unroll
  for (int i = 0; i < 3; ++i) { float d = v[i] - mu; qq += d*d; }
  #pragma unroll
  for (int off = 1; off < 64; off <<= 1) qq += __shfl_xor(qq, off);
  if ((tid & 63) == 0) s2[tid>>6] = qq;
  __syncthreads();
  const float rs = rsqrtf((s2[0] + s2[1]) * (1.0f/384.0f) + 1e-5f);
  #pragma unroll
  for (int i = 0; i < 3; ++i) {
    int j = tid + i*128;
    out[(size_t)row*PDM + j] = (v[i] - mu) * rs * w[j] + bb[j];
  }
}

// ---------------------------------------------------------------- conv1d(DC=4, causal) + silu
__global__ __launch_bounds__(256) void conv_kernel(const float* __restrict__ xz,
                                                   const float* __restrict__ cw,
                                                   const float* __restrict__ cb,
                                                   float* __restrict__ xin) {
  const int row = blockIdx.y;
  const int d = blockIdx.x*256 + threadIdx.x;
  const int l = row & 127;
  const int bbase = row - l;
  float acc = cb[d];
  #pragma unroll
  for (int k = 0; k < 4; ++k) {
    int ll = l + k - 3;
    if (ll >= 0) acc = fmaf(xz[(size_t)(bbase+ll)*1536 + d], cw[d*4+k], acc);
  }
  float s = 1.0f / (1.0f + expf(-acc));
  xin[(size_t)row*PDI + d] = acc * s;
}

// ---------------------------------------------------------------- dbl = xin @ xp_w^T  (N=56)
__global__ __launch_bounds__(64) void xp_kernel(const float* __restrict__ xin,
                                                const float* __restrict__ w,
                                                float* __restrict__ dbl) {
  const int row = blockIdx.x;
  const int e = threadIdx.x;
  if (e >= 56) return;
  const float4* a = (const float4*)(xin + (size_t)row*PDI);
  const float4* wr = (const float4*)(w + (size_t)e*PDI);
  float acc = 0.f;
  for (int k = 0; k < 192; ++k) {
    float4 av = a[k], wv = wr[k];
    acc = fmaf(av.x, wv.x, fmaf(av.y, wv.y, fmaf(av.z, wv.z, fmaf(av.w, wv.w, acc))));
  }
  dbl[(size_t)row*56 + e] = acc;
}

// ---------------------------------------------------------------- dt = softplus(...)
__global__ __launch_bounds__(256) void dt_kernel(const float* __restrict__ dbl,
                                                 const float* __restrict__ dtw,
                                                 const float* __restrict__ dtbias,
                                                 float* __restrict__ dt) {
  const int row = blockIdx.y;
  const int d = blockIdx.x*256 + threadIdx.x;
  const float* br = dbl + (size_t)row*56;
  const float* wr = dtw + (size_t)d*24;
  float acc = dtbias[d];
  #pragma unroll
  for (int r = 0; r < 24; ++r) acc = fmaf(br[r], wr[r], acc);
  dt[(size_t)row*PDI + d] = log1pf(expf(-fabsf(acc))) + fmaxf(acc, 0.0f);
}

// ---------------------------------------------------------------- selective scan
__global__ __launch_bounds__(256) void scan_kernel(const float* __restrict__ dt,
                                                   const float* __restrict__ xin,
                                                   const float* __restrict__ dbl,
                                                   const float* __restrict__ alog,
                                                   const float* __restrict__ dp,
                                                   float* __restrict__ y) {
  const int s = threadIdx.x & 15;
  const int dl = threadIdx.x >> 4;
  const int d = blockIdx.x*16 + dl;
  const int b = blockIdx.y;
  const float A = -expf(alog[d*16 + s]);
  const float Dv = dp[d];
  float h = 0.f;
  for (int l = 0; l < 128; ++l) {
    const int ro = b*128 + l;
    float dtv = dt[(size_t)ro*PDI + d];
    float xv  = xin[(size_t)ro*PDI + d];
    float Bv  = dbl[(size_t)ro*56 + 24 + s];
    float Cv  = dbl[(size_t)ro*56 + 40 + s];
    float dA = expf(dtv * A);
    h = fmaf(dA, h, dtv * xv * Bv);
    float p = h * Cv;
    p += __shfl_xor(p, 1);
    p += __shfl_xor(p, 2);
    p += __shfl_xor(p, 4);
    p += __shfl_xor(p, 8);
    if (s == 0) y[(size_t)ro*PDI + d] = fmaf(Dv, xv, p);
  }
}

// ---------------------------------------------------------------- y*silu(z) -> bf16
__global__ __launch_bounds__(256) void gate_kernel(const float* __restrict__ y,
                                                   const float* __restrict__ xz,
                                                   ushort_t* __restrict__ yb) {
  const int row = blockIdx.y;
  const int d = blockIdx.x*256 + threadIdx.x;
  float z = xz[(size_t)row*1536 + 768 + d];
  float s = 1.0f / (1.0f + expf(-z));
  yb[(size_t)row*PDI + d] = f2bf(y[(size_t)row*PDI + d] * z * s);
}

// ---------------------------------------------------------------- host
extern "C" void kernel_launch(void* const* d_in, const int* in_sizes, int n_in,
                              void* d_out, int out_size, void* d_ws, size_t ws_size,
                              hipStream_t stream) {
  const float* xyz    = (const float*)d_in[0];
  const float* e1w1   = (const float*)d_in[1];
  const float* e1b1   = (const float*)d_in[2];
  const float* bn1g   = (const float*)d_in[3];
  const float* bn1b   = (const float*)d_in[4];
  const float* e1w2   = (const float*)d_in[5];
  const float* e1b2   = (const float*)d_in[6];
  const float* e2w1   = (const float*)d_in[7];
  const float* e2b1   = (const float*)d_in[8];
  const float* bn2g   = (const float*)d_in[9];
  const float* bn2b   = (const float*)d_in[10];
  const float* e2w2   = (const float*)d_in[11];
  const float* e2b2   = (const float*)d_in[12];
  const float* pw1    = (const float*)d_in[13];
  const float* pb1    = (const float*)d_in[14];
  const float* pw2    = (const float*)d_in[15];
  const float* pb2    = (const float*)d_in[16];
  const float* in_w   = (const float*)d_in[17];
  const float* conv_w = (const float*)d_in[18];
  const float* conv_b = (const float*)d_in[19];
  const float* xp_w   = (const float*)d_in[20];
  const float* dt_w   = (const float*)d_in[21];
  const float* dt_b   = (const float*)d_in[22];
  const float* A_log  = (const float*)d_in[23];
  const float* Dp     = (const float*)d_in[24];
  const float* out_w  = (const float*)d_in[25];
  const float* lnw    = (const float*)d_in[26];
  const float* lnb    = (const float*)d_in[27];
  const float* fnw    = (const float*)d_in[28];
  const float* fnb    = (const float*)d_in[29];

  char* ws = (char*)d_ws;
  size_t off = 0;
  auto alloc = [&](size_t bytes) { void* p = ws + off; off += (bytes + 255) & ~(size_t)255; return p; };
  int*      cidx    = (int*)     alloc(PB*PG*4);
  float*    centerb = (float*)   alloc(ROWS*3*4);
  float*    nbx     = (float*)   alloc(ROWS*PM*3*4);
  ushort_t* concat  = (ushort_t*)alloc((size_t)ROWS*PM*512*2);   // 64 MB
  ushort_t* f3      = (ushort_t*)alloc((size_t)ROWS*PM*512*2);   // 64 MB
  float*    hbuf    = (float*)   alloc((size_t)ROWS*PDM*4);
  float*    resid   = (float*)   alloc((size_t)ROWS*PDM*4);
  ushort_t* xlnb    = (ushort_t*)alloc((size_t)ROWS*PDM*2);
  float*    xz      = (float*)   alloc((size_t)ROWS*1536*4);
  float*    xin     = (float*)   alloc((size_t)ROWS*PDI*4);
  float*    dbl     = (float*)   alloc((size_t)ROWS*56*4);
  float*    dtb     = (float*)   alloc((size_t)ROWS*PDI*4);
  float*    yscan   = (float*)   alloc((size_t)ROWS*PDI*4);
  ushort_t* ybufb   = (ushort_t*)alloc((size_t)ROWS*PDI*2);
  ushort_t* e2w1b   = (ushort_t*)alloc((size_t)512*512*2);
  ushort_t* e2w2b   = (ushort_t*)alloc((size_t)384*512*2);
  ushort_t* in_wb   = (ushort_t*)alloc((size_t)12*1536*384*2);
  ushort_t* out_wb  = (ushort_t*)alloc((size_t)12*384*768*2);

  // weight conversions
  cvt_kernel<<<(512*512+255)/256, 256, 0, stream>>>(e2w1, e2w1b, 512*512);
  cvt_kernel<<<(384*512+255)/256, 256, 0, stream>>>(e2w2, e2w2b, 384*512);
  cvt_kernel<<<(12*1536*384+255)/256, 256, 0, stream>>>(in_w, in_wb, 12*1536*384);
  cvt_kernel<<<(12*384*768+255)/256, 256, 0, stream>>>(out_w, out_wb, 12*384*768);

  fps_kernel<<<PB, 256, 0, stream>>>(xyz, cidx);
  knn_kernel<<<ROWS, 256, 0, stream>>>(xyz, cidx, nbx, centerb);
  embed1_kernel<<<ROWS, 256, 0, stream>>>(nbx, e1w1, e1b1, bn1g, bn1b, e1w2, e1b2, concat);

  // stage C: (65536,512)@(512,512)^T, bn+relu -> bf16 f3
  mfma_gemm<4,4,1><<<dim3(4, 512), 256, 0, stream>>>(
      concat, 512, e2w1b, 512, nullptr, f3, 512, 512, e2b1, bn2g, bn2b);
  // stage D: (65536,512)@(384,512)^T, +bias, group-max -> tokens (hbuf)
  mfma_gemm<4,4,2><<<dim3(3, 512), 256, 0, stream>>>(
      f3, 512, e2w2b, 512, hbuf, nullptr, PDM, 512, e2b2, nullptr, nullptr);

  pos_kernel<<<ROWS, 128, 0, stream>>>(centerb, pw1, pb1, pw2, pb2, hbuf);

  for (int i = 0; i < 12; ++i) {
    prenorm_kernel<<<ROWS, 128, 0, stream>>>(hbuf, resid, lnw + i*384, lnb + i*384, xlnb, (i == 0) ? 1 : 0);
    // in-proj: (2048,384)@(1536,384)^T -> xz fp32
    mfma_gemm<4,4,0><<<dim3(12, 16), 256, 0, stream>>>(
        xlnb, PDM, in_wb + (size_t)i*1536*384, PDM, xz, nullptr, 1536, PDM,
        nullptr, nullptr, nullptr);
    conv_kernel<<<dim3(3, ROWS), 256, 0, stream>>>(xz, conv_w + (size_t)i*768*4, conv_b + (size_t)i*768, xin);
    xp_kernel<<<ROWS, 64, 0, stream>>>(xin, xp_w + (size_t)i*56*768, dbl);
    dt_kernel<<<dim3(3, ROWS), 256, 0, stream>>>(dbl, dt_w + (size_t)i*768*24, dt_b + (size_t)i*768, dtb);
    scan_kernel<<<dim3(48, PB), 256, 0, stream>>>(dtb, xin, dbl, A_log + (size_t)i*768*16, Dp + (size_t)i*768, yscan);
    gate_kernel<<<dim3(3, ROWS), 256, 0, stream>>>(yscan, xz, ybufb);
    // out-proj: (2048,768)@(384,768)^T -> hbuf fp32
    mfma_gemm<2,2,0><<<dim3(6, 32), 256, 0, stream>>>(
        ybufb, PDI, out_wb + (size_t)i*384*768, PDI, hbuf, nullptr, PDM, PDI,
        nullptr, nullptr, nullptr);
  }

  final_kernel<<<ROWS, 128, 0, stream>>>(hbuf, resid, fnw, fnb, (float*)d_out);
}